// Round 1
// baseline (1537.902 us; speedup 1.0000x reference)
//
#include <hip/hip_runtime.h>
#include <cstdint>
#include <cstddef>

#define N_TOK  8192
#define HDIM   2048
#define NEXP   8
#define KCAP   1024
#define DFF    5461
#define DFF_PB 5504   // padded N for WgT/WuT (rows of transposed weights)
#define DFF_PA 5472   // padded K for act / gemm2 (multiple of 32)

typedef unsigned short u16;
typedef short bf16x8 __attribute__((ext_vector_type(8)));
typedef float f32x4  __attribute__((ext_vector_type(4)));

__device__ __forceinline__ u16 f2bf(float f) {
  uint32_t u = __float_as_uint(f);
  uint32_t r = (u + 0x7FFFu + ((u >> 16) & 1u)) >> 16;
  return (u16)r;
}

__device__ __forceinline__ uint32_t rotl32(uint32_t v, int d) {
  return (v << d) | (v >> (32 - d));
}

// JAX threefry2x32, key = (0, 42)  [jax.random.key(42)]
// Partitionable scheme (JAX >= 0.5 default): counter = (hi=0, lo=i), bits = x0 ^ x1.
// (Classic split-halves scheme kept in comments as the round-2 fallback.)
__device__ uint32_t threefry_bits(uint32_t idx) {
  const uint32_t ks0 = 0u, ks1 = 42u, ks2 = 0u ^ 42u ^ 0x1BD11BDAu;
  uint32_t x0 = 0u + ks0;       // counts_hi + ks0
  uint32_t x1 = idx + ks1;      // counts_lo + ks1
  // classic scheme (fallback):
  //   uint32_t p = idx & 32767u; x0 = p + ks0; x1 = (p + 32768u) + ks1;
  //   ... return (idx < 32768u) ? x0 : x1;
#define TFR(d) { x0 += x1; x1 = rotl32(x1, d); x1 ^= x0; }
  TFR(13) TFR(15) TFR(26) TFR(6)
  x0 += ks1; x1 += ks2 + 1u;
  TFR(17) TFR(29) TFR(16) TFR(24)
  x0 += ks2; x1 += ks0 + 2u;
  TFR(13) TFR(15) TFR(26) TFR(6)
  x0 += ks0; x1 += ks1 + 3u;
  TFR(17) TFR(29) TFR(16) TFR(24)
  x0 += ks1; x1 += ks2 + 4u;
  TFR(13) TFR(15) TFR(26) TFR(6)
  x0 += ks2; x1 += ks0 + 5u;
#undef TFR
  return x0 ^ x1;
}

// ---------------- router: clean_h + gumbel -> softmax, stored transposed [E][n_tok]
__global__ __launch_bounds__(256) void router_kernel(const float* __restrict__ x,
    const float* __restrict__ rw, const float* __restrict__ rb,
    float* __restrict__ SmT)
{
  const int lane = threadIdx.x & 63;
  const int wid  = threadIdx.x >> 6;
  const int t = blockIdx.x * 4 + wid;     // one token per wave
  const float* xr = x + (size_t)t * HDIM;
  float acc[8] = {0.f,0.f,0.f,0.f,0.f,0.f,0.f,0.f};
#pragma unroll
  for (int it = 0; it < HDIM / 64; ++it) {
    int h = lane + it * 64;
    float xv = xr[h];
    const float4* wp = (const float4*)(rw + h * 8);
    float4 w0 = wp[0], w1 = wp[1];
    acc[0] = fmaf(xv, w0.x, acc[0]);
    acc[1] = fmaf(xv, w0.y, acc[1]);
    acc[2] = fmaf(xv, w0.z, acc[2]);
    acc[3] = fmaf(xv, w0.w, acc[3]);
    acc[4] = fmaf(xv, w1.x, acc[4]);
    acc[5] = fmaf(xv, w1.y, acc[5]);
    acc[6] = fmaf(xv, w1.z, acc[6]);
    acc[7] = fmaf(xv, w1.w, acc[7]);
  }
#pragma unroll
  for (int m = 32; m >= 1; m >>= 1) {
#pragma unroll
    for (int e = 0; e < 8; ++e) acc[e] += __shfl_xor(acc[e], m, 64);
  }
  if (lane == 0) {
    float h[8];
#pragma unroll
    for (int e = 0; e < 8; ++e) {
      uint32_t bits = threefry_bits((uint32_t)(t * 8 + e));
      float u = __uint_as_float((bits >> 9) | 0x3f800000u) - 1.0f;
      u = fmaxf(u, 0.0f);
      float g = -logf(-logf(u + 1e-10f) + 1e-10f);
      h[e] = acc[e] + rb[e] + g;
    }
    float mx = h[0];
#pragma unroll
    for (int e = 1; e < 8; ++e) mx = fmaxf(mx, h[e]);
    float ex[8]; float s = 0.f;
#pragma unroll
    for (int e = 0; e < 8; ++e) { ex[e] = expf(h[e] - mx); s += ex[e]; }
#pragma unroll
    for (int e = 0; e < 8; ++e) SmT[e * N_TOK + t] = ex[e] / s;
  }
}

// ---------------- exact top-1024-of-8192 per expert via 4-pass radix select
__global__ __launch_bounds__(1024) void select_topk(const float* __restrict__ SmT,
    uint32_t* __restrict__ selTok, float* __restrict__ selW)
{
  const int e = blockIdx.x;
  const int tid = threadIdx.x;
  const float* v = SmT + (size_t)e * N_TOK;
  __shared__ uint32_t hist[256];
  __shared__ uint32_t sh_byte, sh_kk, sh_cnt, sh_eqc;
  uint32_t bitsv[8];
#pragma unroll
  for (int i = 0; i < 8; ++i) bitsv[i] = __float_as_uint(v[tid + i * 1024]);
  uint32_t prefix = 0;
  uint32_t kk = KCAP;
  for (int s = 3; s >= 0; --s) {
    if (tid < 256) hist[tid] = 0;
    __syncthreads();
    uint32_t himask = (s == 3) ? 0u : (0xFFFFFFFFu << ((s + 1) * 8));
#pragma unroll
    for (int i = 0; i < 8; ++i) {
      uint32_t b = bitsv[i];
      if ((b & himask) == prefix) atomicAdd(&hist[(b >> (s * 8)) & 255u], 1u);
    }
    __syncthreads();
    if (tid == 0) {
      uint32_t cum = 0; uint32_t bsel = 0, kn = kk;
      for (int b = 255; b >= 0; --b) {
        uint32_t c = hist[b];
        if (cum + c >= kk) { bsel = (uint32_t)b; kn = kk - cum; break; }
        cum += c;
      }
      sh_byte = bsel; sh_kk = kn;
    }
    __syncthreads();
    prefix |= sh_byte << (s * 8);
    kk = sh_kk;
  }
  const uint32_t T = prefix;     // bit pattern of the 1024th-largest value
  const uint32_t need = kk;      // how many ==T belong in top-k
  if (tid == 0) { sh_cnt = 0; sh_eqc = 0; }
  __syncthreads();
#pragma unroll
  for (int i = 0; i < 8; ++i) {
    uint32_t b = bitsv[i];
    if (b > T) {
      uint32_t p = atomicAdd(&sh_cnt, 1u);
      selTok[e * KCAP + p] = (uint32_t)(tid + i * 1024);
      selW[e * KCAP + p] = __uint_as_float(b);
    } else if (b == T) {
      atomicAdd(&sh_eqc, 1u);
    }
  }
  __syncthreads();
  if (sh_eqc == need) {
#pragma unroll
    for (int i = 0; i < 8; ++i) {
      if (bitsv[i] == T) {
        uint32_t p = atomicAdd(&sh_cnt, 1u);
        selTok[e * KCAP + p] = (uint32_t)(tid + i * 1024);
        selW[e * KCAP + p] = __uint_as_float(T);
      }
    }
  } else if (tid == 0) {   // exact-duplicate corner: JAX ties -> lowest index
    uint32_t p = sh_cnt, rem = need;
    for (int t = 0; t < N_TOK && rem > 0u; ++t) {
      if (__float_as_uint(v[t]) == T) {
        selTok[e * KCAP + p] = (uint32_t)t;
        selW[e * KCAP + p] = __uint_as_float(T);
        ++p; --rem;
      }
    }
  }
}

// ---------------- gather selected token rows, fp32 -> bf16
__global__ __launch_bounds__(256) void gather_kernel(const float* __restrict__ x,
    const uint32_t* __restrict__ selTok, u16* __restrict__ Xsel)
{
  const int slot = blockIdx.x;
  const int tid = threadIdx.x;
  const uint32_t tok = selTok[slot];
  const float4* src = (const float4*)(x + (size_t)tok * HDIM);
  float4 a = src[tid * 2], b = src[tid * 2 + 1];
  union { u16 h[8]; uint4 vv; } pk;
  pk.h[0] = f2bf(a.x); pk.h[1] = f2bf(a.y); pk.h[2] = f2bf(a.z); pk.h[3] = f2bf(a.w);
  pk.h[4] = f2bf(b.x); pk.h[5] = f2bf(b.y); pk.h[6] = f2bf(b.z); pk.h[7] = f2bf(b.w);
  ((uint4*)(Xsel + (size_t)slot * HDIM))[tid] = pk.vv;
}

// ---------------- zero the K-pad columns of act (cols DFF..DFF_PA)
__global__ __launch_bounds__(256) void pad_act_kernel(u16* __restrict__ act) {
  int idx = blockIdx.x * 256 + threadIdx.x;   // 8192*11 total
  int row = idx / 11, col = idx % 11;
  act[(size_t)row * DFF_PA + (DFF + col)] = 0;
}

// ---------------- transpose + fp32->bf16: out[j][i] = in[i][j], zero-padded
__global__ __launch_bounds__(256) void transpose_convert(const float* __restrict__ in,
    int rows_in, int cols_in, u16* __restrict__ out, int out_cols)
{
  __shared__ float tile[32][33];
  const int bi = blockIdx.y;   // tile along in-rows
  const int bj = blockIdx.x;   // tile along in-cols
  const int tx = threadIdx.x, ty = threadIdx.y;
#pragma unroll
  for (int t = 0; t < 4; ++t) {
    int r = bi * 32 + ty + t * 8, c = bj * 32 + tx;
    float vv = (r < rows_in && c < cols_in) ? in[(size_t)r * cols_in + c] : 0.0f;
    tile[ty + t * 8][tx] = vv;
  }
  __syncthreads();
#pragma unroll
  for (int t = 0; t < 4; ++t) {
    int oj = bj * 32 + ty + t * 8;   // out row (= in col)
    int oi = bi * 32 + tx;           // out col (= in row)
    out[(size_t)oj * out_cols + oi] = f2bf(tile[tx][ty + t * 8]);
  }
}

// ---------------- async global->LDS staging helper
#if defined(__has_builtin)
#  if __has_builtin(__builtin_amdgcn_global_load_lds)
#    define HAVE_GLD 1
#  endif
#endif
#ifdef HAVE_GLD
#define GLD16(gp, lp) __builtin_amdgcn_global_load_lds( \
    (const __attribute__((address_space(1))) void*)(gp), \
    (__attribute__((address_space(3))) void*)(lp), 16, 0, 0)
#endif

// ---------------- GEMM1: act = silu(Xsel*WgT + bg) .* (Xsel*WuT + bu), bf16 out
__global__ __launch_bounds__(256) void gemm1_kernel(
    const u16* __restrict__ Xsel,  // [8192][2048] bf16
    const u16* __restrict__ WgT,   // [5504][2048] bf16 (N-major, K-contig)
    const u16* __restrict__ WuT,   // [5504][2048]
    const float* __restrict__ bg, const float* __restrict__ bu,
    u16* __restrict__ act)         // [8192][5472] bf16
{
  __shared__ u16 As [128 * 32];
  __shared__ u16 Bgs[128 * 32];
  __shared__ u16 Bus[128 * 32];
  const int tid = threadIdx.x;
  const int bn = blockIdx.x, bm = blockIdx.y;
  const int lane = tid & 63, wid = tid >> 6;
  const int wr = wid >> 1, wc = wid & 1;
  const int c0 = tid, c1 = tid + 256;                 // 16B chunk ids (512 per tile)
  const int r0 = c0 >> 2, ko0 = (c0 & 3) * 8;
  const int r1 = c1 >> 2, ko1 = (c1 & 3) * 8;

  const u16* a_g0  = Xsel + (size_t)(bm * 128 + r0) * HDIM + ko0;
  const u16* a_g1  = Xsel + (size_t)(bm * 128 + r1) * HDIM + ko1;
  const u16* bg_g0 = WgT  + (size_t)(bn * 128 + r0) * HDIM + ko0;
  const u16* bg_g1 = WgT  + (size_t)(bn * 128 + r1) * HDIM + ko1;
  const u16* bu_g0 = WuT  + (size_t)(bn * 128 + r0) * HDIM + ko0;
  const u16* bu_g1 = WuT  + (size_t)(bn * 128 + r1) * HDIM + ko1;
  u16* a_l0 = As  + c0 * 8; u16* a_l1 = As  + c1 * 8;
  u16* g_l0 = Bgs + c0 * 8; u16* g_l1 = Bgs + c1 * 8;
  u16* u_l0 = Bus + c0 * 8; u16* u_l1 = Bus + c1 * 8;

  f32x4 accg[4][4], accu[4][4];
  const f32x4 z4 = {0.f, 0.f, 0.f, 0.f};
#pragma unroll
  for (int i = 0; i < 4; ++i)
#pragma unroll
    for (int j = 0; j < 4; ++j) { accg[i][j] = z4; accu[i][j] = z4; }

  const int fr = lane & 15;
  const int fk = (lane >> 4) * 8;
  const int aoff = (wr * 64 + fr) * 32 + fk;
  const int boff = (wc * 64 + fr) * 32 + fk;

  for (int k0 = 0; k0 < HDIM; k0 += 32) {
#ifdef HAVE_GLD
    GLD16(a_g0 + k0, a_l0);  GLD16(a_g1 + k0, a_l1);
    GLD16(bg_g0 + k0, g_l0); GLD16(bg_g1 + k0, g_l1);
    GLD16(bu_g0 + k0, u_l0); GLD16(bu_g1 + k0, u_l1);
#else
    *(bf16x8*)a_l0 = *(const bf16x8*)(a_g0 + k0);
    *(bf16x8*)a_l1 = *(const bf16x8*)(a_g1 + k0);
    *(bf16x8*)g_l0 = *(const bf16x8*)(bg_g0 + k0);
    *(bf16x8*)g_l1 = *(const bf16x8*)(bg_g1 + k0);
    *(bf16x8*)u_l0 = *(const bf16x8*)(bu_g0 + k0);
    *(bf16x8*)u_l1 = *(const bf16x8*)(bu_g1 + k0);
#endif
    __syncthreads();
    bf16x8 af[4], bgf[4], buf2[4];
#pragma unroll
    for (int i = 0; i < 4; ++i) af[i] = *(const bf16x8*)&As[aoff + i * 16 * 32];
#pragma unroll
    for (int j = 0; j < 4; ++j) {
      bgf[j]  = *(const bf16x8*)&Bgs[boff + j * 16 * 32];
      buf2[j] = *(const bf16x8*)&Bus[boff + j * 16 * 32];
    }
#pragma unroll
    for (int i = 0; i < 4; ++i)
#pragma unroll
      for (int j = 0; j < 4; ++j) {
        accg[i][j] = __builtin_amdgcn_mfma_f32_16x16x32_bf16(af[i], bgf[j],  accg[i][j], 0, 0, 0);
        accu[i][j] = __builtin_amdgcn_mfma_f32_16x16x32_bf16(af[i], buf2[j], accu[i][j], 0, 0, 0);
      }
    __syncthreads();
  }
  const int rv = (lane >> 4) * 4;
#pragma unroll
  for (int i = 0; i < 4; ++i) {
#pragma unroll
    for (int v = 0; v < 4; ++v) {
      const int row = bm * 128 + wr * 64 + i * 16 + rv + v;
      u16* arow = act + (size_t)row * DFF_PA;
#pragma unroll
      for (int j = 0; j < 4; ++j) {
        const int col = bn * 128 + wc * 64 + j * 16 + fr;
        if (col < DFF) {
          float gv = accg[i][j][v] + bg[col];
          float uv = accu[i][j][v] + bu[col];
          float sv = gv / (1.0f + expf(-gv));   // silu
          arow[col] = f2bf(sv * uv);
        }
      }
    }
  }
}

// ---------------- GEMM2: y[tok] += G * (act*WdT + bd)  (fp32 atomics)
__global__ __launch_bounds__(256) void gemm2_kernel(
    const u16* __restrict__ act,   // [8192][5472] bf16
    const u16* __restrict__ WdT,   // [2048][5472] bf16
    const float* __restrict__ bd,  // [2048]
    const uint32_t* __restrict__ selTok,
    const float* __restrict__ selW,
    float* __restrict__ y)         // [8192][2048] fp32
{
  __shared__ u16 As[128 * 32];
  __shared__ u16 Bs[128 * 32];
  const int tid = threadIdx.x;
  const int bn = blockIdx.x, bm = blockIdx.y;
  const int lane = tid & 63, wid = tid >> 6;
  const int wr = wid >> 1, wc = wid & 1;
  const int c0 = tid, c1 = tid + 256;
  const int r0 = c0 >> 2, ko0 = (c0 & 3) * 8;
  const int r1 = c1 >> 2, ko1 = (c1 & 3) * 8;

  const u16* a_g0 = act + (size_t)(bm * 128 + r0) * DFF_PA + ko0;
  const u16* a_g1 = act + (size_t)(bm * 128 + r1) * DFF_PA + ko1;
  const u16* b_g0 = WdT + (size_t)(bn * 128 + r0) * DFF_PA + ko0;
  const u16* b_g1 = WdT + (size_t)(bn * 128 + r1) * DFF_PA + ko1;
  u16* a_l0 = As + c0 * 8; u16* a_l1 = As + c1 * 8;
  u16* b_l0 = Bs + c0 * 8; u16* b_l1 = Bs + c1 * 8;

  f32x4 acc[4][4];
  const f32x4 z4 = {0.f, 0.f, 0.f, 0.f};
#pragma unroll
  for (int i = 0; i < 4; ++i)
#pragma unroll
    for (int j = 0; j < 4; ++j) acc[i][j] = z4;

  const int fr = lane & 15;
  const int fk = (lane >> 4) * 8;
  const int aoff = (wr * 64 + fr) * 32 + fk;
  const int boff = (wc * 64 + fr) * 32 + fk;

  for (int k0 = 0; k0 < DFF_PA; k0 += 32) {
#ifdef HAVE_GLD
    GLD16(a_g0 + k0, a_l0); GLD16(a_g1 + k0, a_l1);
    GLD16(b_g0 + k0, b_l0); GLD16(b_g1 + k0, b_l1);
#else
    *(bf16x8*)a_l0 = *(const bf16x8*)(a_g0 + k0);
    *(bf16x8*)a_l1 = *(const bf16x8*)(a_g1 + k0);
    *(bf16x8*)b_l0 = *(const bf16x8*)(b_g0 + k0);
    *(bf16x8*)b_l1 = *(const bf16x8*)(b_g1 + k0);
#endif
    __syncthreads();
    bf16x8 af[4], bf[4];
#pragma unroll
    for (int i = 0; i < 4; ++i) af[i] = *(const bf16x8*)&As[aoff + i * 16 * 32];
#pragma unroll
    for (int j = 0; j < 4; ++j) bf[j] = *(const bf16x8*)&Bs[boff + j * 16 * 32];
#pragma unroll
    for (int i = 0; i < 4; ++i)
#pragma unroll
      for (int j = 0; j < 4; ++j)
        acc[i][j] = __builtin_amdgcn_mfma_f32_16x16x32_bf16(af[i], bf[j], acc[i][j], 0, 0, 0);
    __syncthreads();
  }
  const int rv = (lane >> 4) * 4;
#pragma unroll
  for (int i = 0; i < 4; ++i) {
#pragma unroll
    for (int v = 0; v < 4; ++v) {
      const int row = bm * 128 + wr * 64 + i * 16 + rv + v;   // slot
      const uint32_t tok = selTok[row];
      const float w = selW[row];
      float* yrow = y + (size_t)tok * HDIM;
#pragma unroll
      for (int j = 0; j < 4; ++j) {
        const int col = bn * 128 + wc * 64 + j * 16 + fr;
        atomicAdd(&yrow[col], w * (acc[i][j][v] + bd[col]));
      }
    }
  }
}

extern "C" void kernel_launch(void* const* d_in, const int* in_sizes, int n_in,
                              void* d_out, int out_size, void* d_ws, size_t ws_size,
                              hipStream_t stream) {
  const float* x      = (const float*)d_in[0];
  const float* rw     = (const float*)d_in[1];
  const float* rb     = (const float*)d_in[2];
  const float* w_gate = (const float*)d_in[3];
  const float* b_gate = (const float*)d_in[4];
  const float* w_up   = (const float*)d_in[5];
  const float* b_up   = (const float*)d_in[6];
  const float* w_down = (const float*)d_in[7];
  const float* b_down = (const float*)d_in[8];
  float* y = (float*)d_out;

  uint8_t* ws = (uint8_t*)d_ws;
  float*    SmT    = (float*)(ws + 0);              //   262144 B  [8][8192] f32
  uint32_t* selTok = (uint32_t*)(ws + 262144);      //    32768 B  [8192] u32
  float*    selW   = (float*)(ws + 294912);         //    32768 B  [8192] f32
  u16*      Xsel   = (u16*)(ws + 327680);           // 33554432 B  [8192][2048] bf16
  u16*      WgT    = (u16*)(ws + 33882112ull);      // 22544384 B  [5504][2048] bf16
  u16*      WuT    = (u16*)(ws + 56426496ull);      // 22544384 B
  u16*      WdT    = (u16*)(ws + 78970880ull);      // 22413312 B  [2048][5472] bf16
  u16*      act    = (u16*)(ws + 101384192ull);     // 89653248 B  [8192][5472] bf16
                                                    // total 191037440 B

  hipMemsetAsync(d_out, 0, (size_t)N_TOK * HDIM * sizeof(float), stream);
  transpose_convert<<<dim3(172, 64), dim3(32, 8), 0, stream>>>(w_gate, 2048, DFF, WgT, 2048);
  transpose_convert<<<dim3(172, 64), dim3(32, 8), 0, stream>>>(w_up,   2048, DFF, WuT, 2048);
  transpose_convert<<<dim3(64, 171), dim3(32, 8), 0, stream>>>(w_down, DFF, 2048, WdT, DFF_PA);
  router_kernel<<<N_TOK / 4, 256, 0, stream>>>(x, rw, rb, SmT);
  select_topk<<<NEXP, 1024, 0, stream>>>(SmT, selTok, selW);
  gather_kernel<<<N_TOK, 256, 0, stream>>>(x, selTok, Xsel);
  pad_act_kernel<<<(N_TOK * 11) / 256, 256, 0, stream>>>(act);
  gemm1_kernel<<<dim3(43, 64), 256, 0, stream>>>(Xsel, WgT, WuT, b_gate, b_up, act);
  gemm2_kernel<<<dim3(16, 64), 256, 0, stream>>>(act, WdT, b_down, selTok, selW, y);
}

// Round 2
// 1158.004 us; speedup vs baseline: 1.3281x; 1.3281x over previous
//
#include <hip/hip_runtime.h>
#include <cstdint>
#include <cstddef>

#define N_TOK  8192
#define HDIM   2048
#define NEXP   8
#define KCAP   1024
#define DFF    5461
#define DFF_PB 5504   // padded N for WgT/WuT (rows of transposed weights)
#define DFF_PA 5472   // padded K for act / gemm2 (multiple of 32)

typedef unsigned short u16;
typedef short bf16x8 __attribute__((ext_vector_type(8)));
typedef float f32x4  __attribute__((ext_vector_type(4)));

__device__ __forceinline__ u16 f2bf(float f) {
  uint32_t u = __float_as_uint(f);
  uint32_t r = (u + 0x7FFFu + ((u >> 16) & 1u)) >> 16;
  return (u16)r;
}

__device__ __forceinline__ uint32_t rotl32(uint32_t v, int d) {
  return (v << d) | (v >> (32 - d));
}

// JAX threefry2x32, key = (0, 42), partitionable scheme: counter=(0,i), bits = x0^x1.
__device__ uint32_t threefry_bits(uint32_t idx) {
  const uint32_t ks0 = 0u, ks1 = 42u, ks2 = 0u ^ 42u ^ 0x1BD11BDAu;
  uint32_t x0 = 0u + ks0;
  uint32_t x1 = idx + ks1;
#define TFR(d) { x0 += x1; x1 = rotl32(x1, d); x1 ^= x0; }
  TFR(13) TFR(15) TFR(26) TFR(6)
  x0 += ks1; x1 += ks2 + 1u;
  TFR(17) TFR(29) TFR(16) TFR(24)
  x0 += ks2; x1 += ks0 + 2u;
  TFR(13) TFR(15) TFR(26) TFR(6)
  x0 += ks0; x1 += ks1 + 3u;
  TFR(17) TFR(29) TFR(16) TFR(24)
  x0 += ks1; x1 += ks2 + 4u;
  TFR(13) TFR(15) TFR(26) TFR(6)
  x0 += ks2; x1 += ks0 + 5u;
#undef TFR
  return x0 ^ x1;
}

// ---------------- router: clean_h + gumbel -> softmax, stored transposed [E][n_tok]
__global__ __launch_bounds__(256) void router_kernel(const float* __restrict__ x,
    const float* __restrict__ rw, const float* __restrict__ rb,
    float* __restrict__ SmT)
{
  const int lane = threadIdx.x & 63;
  const int wid  = threadIdx.x >> 6;
  const int t = blockIdx.x * 4 + wid;     // one token per wave
  const float* xr = x + (size_t)t * HDIM;
  float acc[8] = {0.f,0.f,0.f,0.f,0.f,0.f,0.f,0.f};
#pragma unroll
  for (int it = 0; it < HDIM / 64; ++it) {
    int h = lane + it * 64;
    float xv = xr[h];
    const float4* wp = (const float4*)(rw + h * 8);
    float4 w0 = wp[0], w1 = wp[1];
    acc[0] = fmaf(xv, w0.x, acc[0]);
    acc[1] = fmaf(xv, w0.y, acc[1]);
    acc[2] = fmaf(xv, w0.z, acc[2]);
    acc[3] = fmaf(xv, w0.w, acc[3]);
    acc[4] = fmaf(xv, w1.x, acc[4]);
    acc[5] = fmaf(xv, w1.y, acc[5]);
    acc[6] = fmaf(xv, w1.z, acc[6]);
    acc[7] = fmaf(xv, w1.w, acc[7]);
  }
#pragma unroll
  for (int m = 32; m >= 1; m >>= 1) {
#pragma unroll
    for (int e = 0; e < 8; ++e) acc[e] += __shfl_xor(acc[e], m, 64);
  }
  if (lane == 0) {
    float h[8];
#pragma unroll
    for (int e = 0; e < 8; ++e) {
      uint32_t bits = threefry_bits((uint32_t)(t * 8 + e));
      float u = __uint_as_float((bits >> 9) | 0x3f800000u) - 1.0f;
      u = fmaxf(u, 0.0f);
      float g = -logf(-logf(u + 1e-10f) + 1e-10f);
      h[e] = acc[e] + rb[e] + g;
    }
    float mx = h[0];
#pragma unroll
    for (int e = 1; e < 8; ++e) mx = fmaxf(mx, h[e]);
    float ex[8]; float s = 0.f;
#pragma unroll
    for (int e = 0; e < 8; ++e) { ex[e] = expf(h[e] - mx); s += ex[e]; }
#pragma unroll
    for (int e = 0; e < 8; ++e) SmT[e * N_TOK + t] = ex[e] / s;
  }
}

// ---------------- exact top-1024-of-8192 per expert via 4-pass radix select
__global__ __launch_bounds__(1024) void select_topk(const float* __restrict__ SmT,
    uint32_t* __restrict__ selTok, float* __restrict__ selW)
{
  const int e = blockIdx.x;
  const int tid = threadIdx.x;
  const float* v = SmT + (size_t)e * N_TOK;
  __shared__ uint32_t hist[256];
  __shared__ uint32_t sh_byte, sh_kk, sh_cnt, sh_eqc;
  uint32_t bitsv[8];
#pragma unroll
  for (int i = 0; i < 8; ++i) bitsv[i] = __float_as_uint(v[tid + i * 1024]);
  uint32_t prefix = 0;
  uint32_t kk = KCAP;
  for (int s = 3; s >= 0; --s) {
    if (tid < 256) hist[tid] = 0;
    __syncthreads();
    uint32_t himask = (s == 3) ? 0u : (0xFFFFFFFFu << ((s + 1) * 8));
#pragma unroll
    for (int i = 0; i < 8; ++i) {
      uint32_t b = bitsv[i];
      if ((b & himask) == prefix) atomicAdd(&hist[(b >> (s * 8)) & 255u], 1u);
    }
    __syncthreads();
    if (tid == 0) {
      uint32_t cum = 0; uint32_t bsel = 0, kn = kk;
      for (int b = 255; b >= 0; --b) {
        uint32_t c = hist[b];
        if (cum + c >= kk) { bsel = (uint32_t)b; kn = kk - cum; break; }
        cum += c;
      }
      sh_byte = bsel; sh_kk = kn;
    }
    __syncthreads();
    prefix |= sh_byte << (s * 8);
    kk = sh_kk;
  }
  const uint32_t T = prefix;
  const uint32_t need = kk;
  if (tid == 0) { sh_cnt = 0; sh_eqc = 0; }
  __syncthreads();
#pragma unroll
  for (int i = 0; i < 8; ++i) {
    uint32_t b = bitsv[i];
    if (b > T) {
      uint32_t p = atomicAdd(&sh_cnt, 1u);
      selTok[e * KCAP + p] = (uint32_t)(tid + i * 1024);
      selW[e * KCAP + p] = __uint_as_float(b);
    } else if (b == T) {
      atomicAdd(&sh_eqc, 1u);
    }
  }
  __syncthreads();
  if (sh_eqc == need) {
#pragma unroll
    for (int i = 0; i < 8; ++i) {
      if (bitsv[i] == T) {
        uint32_t p = atomicAdd(&sh_cnt, 1u);
        selTok[e * KCAP + p] = (uint32_t)(tid + i * 1024);
        selW[e * KCAP + p] = __uint_as_float(T);
      }
    }
  } else if (tid == 0) {
    uint32_t p = sh_cnt, rem = need;
    for (int t = 0; t < N_TOK && rem > 0u; ++t) {
      if (__float_as_uint(v[t]) == T) {
        selTok[e * KCAP + p] = (uint32_t)t;
        selW[e * KCAP + p] = __uint_as_float(T);
        ++p; --rem;
      }
    }
  }
}

// ---------------- gather selected token rows, fp32 -> bf16
__global__ __launch_bounds__(256) void gather_kernel(const float* __restrict__ x,
    const uint32_t* __restrict__ selTok, u16* __restrict__ Xsel)
{
  const int slot = blockIdx.x;
  const int tid = threadIdx.x;
  const uint32_t tok = selTok[slot];
  const float4* src = (const float4*)(x + (size_t)tok * HDIM);
  float4 a = src[tid * 2], b = src[tid * 2 + 1];
  union { u16 h[8]; uint4 vv; } pk;
  pk.h[0] = f2bf(a.x); pk.h[1] = f2bf(a.y); pk.h[2] = f2bf(a.z); pk.h[3] = f2bf(a.w);
  pk.h[4] = f2bf(b.x); pk.h[5] = f2bf(b.y); pk.h[6] = f2bf(b.z); pk.h[7] = f2bf(b.w);
  ((uint4*)(Xsel + (size_t)slot * HDIM))[tid] = pk.vv;
}

// ---------------- zero the K-pad columns of act (cols DFF..DFF_PA)
__global__ __launch_bounds__(256) void pad_act_kernel(u16* __restrict__ act) {
  int idx = blockIdx.x * 256 + threadIdx.x;   // 8192*11 total
  int row = idx / 11, col = idx % 11;
  act[(size_t)row * DFF_PA + (DFF + col)] = 0;
}

// ---------------- transpose + fp32->bf16: out[j][i] = in[i][j], zero-padded
__global__ __launch_bounds__(256) void transpose_convert(const float* __restrict__ in,
    int rows_in, int cols_in, u16* __restrict__ out, int out_cols)
{
  __shared__ float tile[32][33];
  const int bi = blockIdx.y;
  const int bj = blockIdx.x;
  const int tx = threadIdx.x, ty = threadIdx.y;
#pragma unroll
  for (int t = 0; t < 4; ++t) {
    int r = bi * 32 + ty + t * 8, c = bj * 32 + tx;
    float vv = (r < rows_in && c < cols_in) ? in[(size_t)r * cols_in + c] : 0.0f;
    tile[ty + t * 8][tx] = vv;
  }
  __syncthreads();
#pragma unroll
  for (int t = 0; t < 4; ++t) {
    int oj = bj * 32 + ty + t * 8;
    int oi = bi * 32 + tx;
    out[(size_t)oj * out_cols + oi] = f2bf(tile[tx][ty + t * 8]);
  }
}

// ---------------- async global->LDS staging helper
#if defined(__has_builtin)
#  if __has_builtin(__builtin_amdgcn_global_load_lds)
#    define HAVE_GLD 1
#  endif
#endif
#ifdef HAVE_GLD
#define GLD16(gp, lp) __builtin_amdgcn_global_load_lds( \
    (const __attribute__((address_space(1))) void*)(gp), \
    (__attribute__((address_space(3))) void*)(lp), 16, 0, 0)
#endif

// ---------------- GEMM1: act = silu(Xsel*WgT + bg) .* (Xsel*WuT + bu), bf16 out
// Block tile 128(M) x 64(N), fused gate+up. 64 acc AGPRs/wave -> 2 waves/SIMD.
__global__ __launch_bounds__(256, 2) void gemm1_kernel(
    const u16* __restrict__ Xsel,  // [8192][2048] bf16
    const u16* __restrict__ WgT,   // [5504][2048] bf16 (N-major, K-contig)
    const u16* __restrict__ WuT,   // [5504][2048]
    const float* __restrict__ bg, const float* __restrict__ bu,
    u16* __restrict__ act)         // [8192][5472] bf16
{
  __shared__ u16 As [128 * 32];  // 8 KB
  __shared__ u16 Bgs[ 64 * 32];  // 4 KB
  __shared__ u16 Bus[ 64 * 32];  // 4 KB
  const int tid = threadIdx.x;
  const int bn = blockIdx.x, bm = blockIdx.y;
  const int lane = tid & 63, wid = tid >> 6;
  const int wr = wid >> 1, wc = wid & 1;
  // A: 512 chunks of 16B -> 2/thread; Bg,Bu: 256 chunks each -> 1/thread each
  const int c0 = tid, c1 = tid + 256;
  const int r0 = c0 >> 2, ko0 = (c0 & 3) * 8;
  const int r1 = c1 >> 2, ko1 = (c1 & 3) * 8;
  const int rbq = tid >> 2, kob = (tid & 3) * 8;

  const u16* a_g0  = Xsel + (size_t)(bm * 128 + r0) * HDIM + ko0;
  const u16* a_g1  = Xsel + (size_t)(bm * 128 + r1) * HDIM + ko1;
  const u16* bg_g  = WgT  + (size_t)(bn * 64 + rbq) * HDIM + kob;
  const u16* bu_g  = WuT  + (size_t)(bn * 64 + rbq) * HDIM + kob;
  u16* a_l0 = As  + c0 * 8; u16* a_l1 = As + c1 * 8;
  u16* g_l  = Bgs + tid * 8;
  u16* u_l  = Bus + tid * 8;

  f32x4 accg[4][2], accu[4][2];
  const f32x4 z4 = {0.f, 0.f, 0.f, 0.f};
#pragma unroll
  for (int i = 0; i < 4; ++i)
#pragma unroll
    for (int j = 0; j < 2; ++j) { accg[i][j] = z4; accu[i][j] = z4; }

  const int fr = lane & 15;
  const int fk = (lane >> 4) * 8;
  const int aoff = (wr * 64 + fr) * 32 + fk;
  const int boff = (wc * 32 + fr) * 32 + fk;

  for (int k0 = 0; k0 < HDIM; k0 += 32) {
#ifdef HAVE_GLD
    GLD16(a_g0 + k0, a_l0); GLD16(a_g1 + k0, a_l1);
    GLD16(bg_g + k0, g_l);  GLD16(bu_g + k0, u_l);
#else
    *(bf16x8*)a_l0 = *(const bf16x8*)(a_g0 + k0);
    *(bf16x8*)a_l1 = *(const bf16x8*)(a_g1 + k0);
    *(bf16x8*)g_l  = *(const bf16x8*)(bg_g + k0);
    *(bf16x8*)u_l  = *(const bf16x8*)(bu_g + k0);
#endif
    __syncthreads();
    bf16x8 af[4], bgf[2], buf2[2];
#pragma unroll
    for (int i = 0; i < 4; ++i) af[i] = *(const bf16x8*)&As[aoff + i * 16 * 32];
#pragma unroll
    for (int j = 0; j < 2; ++j) {
      bgf[j]  = *(const bf16x8*)&Bgs[boff + j * 16 * 32];
      buf2[j] = *(const bf16x8*)&Bus[boff + j * 16 * 32];
    }
#pragma unroll
    for (int i = 0; i < 4; ++i)
#pragma unroll
      for (int j = 0; j < 2; ++j) {
        accg[i][j] = __builtin_amdgcn_mfma_f32_16x16x32_bf16(af[i], bgf[j],  accg[i][j], 0, 0, 0);
        accu[i][j] = __builtin_amdgcn_mfma_f32_16x16x32_bf16(af[i], buf2[j], accu[i][j], 0, 0, 0);
      }
    __syncthreads();
  }
  const int rv = (lane >> 4) * 4;
#pragma unroll
  for (int i = 0; i < 4; ++i) {
#pragma unroll
    for (int v = 0; v < 4; ++v) {
      const int row = bm * 128 + wr * 64 + i * 16 + rv + v;
      u16* arow = act + (size_t)row * DFF_PA;
#pragma unroll
      for (int j = 0; j < 2; ++j) {
        const int col = bn * 64 + wc * 32 + j * 16 + fr;
        if (col < DFF) {
          float gv = accg[i][j][v] + bg[col];
          float uv = accu[i][j][v] + bu[col];
          float sv = gv / (1.0f + expf(-gv));   // silu
          arow[col] = f2bf(sv * uv);
        }
      }
    }
  }
}

// ---------------- GEMM2: y[tok] += G * (act*WdT + bd)  (fp32 atomics)
__global__ __launch_bounds__(256) void gemm2_kernel(
    const u16* __restrict__ act,   // [8192][5472] bf16
    const u16* __restrict__ WdT,   // [2048][5472] bf16
    const float* __restrict__ bd,  // [2048]
    const uint32_t* __restrict__ selTok,
    const float* __restrict__ selW,
    float* __restrict__ y)         // [8192][2048] fp32
{
  __shared__ u16 As[128 * 32];
  __shared__ u16 Bs[128 * 32];
  const int tid = threadIdx.x;
  const int bn = blockIdx.x, bm = blockIdx.y;
  const int lane = tid & 63, wid = tid >> 6;
  const int wr = wid >> 1, wc = wid & 1;
  const int c0 = tid, c1 = tid + 256;
  const int r0 = c0 >> 2, ko0 = (c0 & 3) * 8;
  const int r1 = c1 >> 2, ko1 = (c1 & 3) * 8;

  const u16* a_g0 = act + (size_t)(bm * 128 + r0) * DFF_PA + ko0;
  const u16* a_g1 = act + (size_t)(bm * 128 + r1) * DFF_PA + ko1;
  const u16* b_g0 = WdT + (size_t)(bn * 128 + r0) * DFF_PA + ko0;
  const u16* b_g1 = WdT + (size_t)(bn * 128 + r1) * DFF_PA + ko1;
  u16* a_l0 = As + c0 * 8; u16* a_l1 = As + c1 * 8;
  u16* b_l0 = Bs + c0 * 8; u16* b_l1 = Bs + c1 * 8;

  f32x4 acc[4][4];
  const f32x4 z4 = {0.f, 0.f, 0.f, 0.f};
#pragma unroll
  for (int i = 0; i < 4; ++i)
#pragma unroll
    for (int j = 0; j < 4; ++j) acc[i][j] = z4;

  const int fr = lane & 15;
  const int fk = (lane >> 4) * 8;
  const int aoff = (wr * 64 + fr) * 32 + fk;
  const int boff = (wc * 64 + fr) * 32 + fk;

  for (int k0 = 0; k0 < DFF_PA; k0 += 32) {
#ifdef HAVE_GLD
    GLD16(a_g0 + k0, a_l0); GLD16(a_g1 + k0, a_l1);
    GLD16(b_g0 + k0, b_l0); GLD16(b_g1 + k0, b_l1);
#else
    *(bf16x8*)a_l0 = *(const bf16x8*)(a_g0 + k0);
    *(bf16x8*)a_l1 = *(const bf16x8*)(a_g1 + k0);
    *(bf16x8*)b_l0 = *(const bf16x8*)(b_g0 + k0);
    *(bf16x8*)b_l1 = *(const bf16x8*)(b_g1 + k0);
#endif
    __syncthreads();
    bf16x8 af[4], bf[4];
#pragma unroll
    for (int i = 0; i < 4; ++i) af[i] = *(const bf16x8*)&As[aoff + i * 16 * 32];
#pragma unroll
    for (int j = 0; j < 4; ++j) bf[j] = *(const bf16x8*)&Bs[boff + j * 16 * 32];
#pragma unroll
    for (int i = 0; i < 4; ++i)
#pragma unroll
      for (int j = 0; j < 4; ++j)
        acc[i][j] = __builtin_amdgcn_mfma_f32_16x16x32_bf16(af[i], bf[j], acc[i][j], 0, 0, 0);
    __syncthreads();
  }
  const int rv = (lane >> 4) * 4;
#pragma unroll
  for (int i = 0; i < 4; ++i) {
#pragma unroll
    for (int v = 0; v < 4; ++v) {
      const int row = bm * 128 + wr * 64 + i * 16 + rv + v;   // slot
      const uint32_t tok = selTok[row];
      const float w = selW[row];
      float* yrow = y + (size_t)tok * HDIM;
#pragma unroll
      for (int j = 0; j < 4; ++j) {
        const int col = bn * 128 + wc * 64 + j * 16 + fr;
        atomicAdd(&yrow[col], w * (acc[i][j][v] + bd[col]));
      }
    }
  }
}

extern "C" void kernel_launch(void* const* d_in, const int* in_sizes, int n_in,
                              void* d_out, int out_size, void* d_ws, size_t ws_size,
                              hipStream_t stream) {
  const float* x      = (const float*)d_in[0];
  const float* rw     = (const float*)d_in[1];
  const float* rb     = (const float*)d_in[2];
  const float* w_gate = (const float*)d_in[3];
  const float* b_gate = (const float*)d_in[4];
  const float* w_up   = (const float*)d_in[5];
  const float* b_up   = (const float*)d_in[6];
  const float* w_down = (const float*)d_in[7];
  const float* b_down = (const float*)d_in[8];
  float* y = (float*)d_out;

  uint8_t* ws = (uint8_t*)d_ws;
  float*    SmT    = (float*)(ws + 0);              //   262144 B
  uint32_t* selTok = (uint32_t*)(ws + 262144);      //    32768 B
  float*    selW   = (float*)(ws + 294912);         //    32768 B
  u16*      Xsel   = (u16*)(ws + 327680);           // 33554432 B
  u16*      WgT    = (u16*)(ws + 33882112ull);      // 22544384 B
  u16*      WuT    = (u16*)(ws + 56426496ull);      // 22544384 B
  u16*      WdT    = (u16*)(ws + 78970880ull);      // 22413312 B
  u16*      act    = (u16*)(ws + 101384192ull);     // 89653248 B

  hipMemsetAsync(d_out, 0, (size_t)N_TOK * HDIM * sizeof(float), stream);
  transpose_convert<<<dim3(172, 64), dim3(32, 8), 0, stream>>>(w_gate, 2048, DFF, WgT, 2048);
  transpose_convert<<<dim3(172, 64), dim3(32, 8), 0, stream>>>(w_up,   2048, DFF, WuT, 2048);
  transpose_convert<<<dim3(64, 171), dim3(32, 8), 0, stream>>>(w_down, DFF, 2048, WdT, DFF_PA);
  router_kernel<<<N_TOK / 4, 256, 0, stream>>>(x, rw, rb, SmT);
  select_topk<<<NEXP, 1024, 0, stream>>>(SmT, selTok, selW);
  gather_kernel<<<N_TOK, 256, 0, stream>>>(x, selTok, Xsel);
  pad_act_kernel<<<(N_TOK * 11) / 256, 256, 0, stream>>>(act);
  gemm1_kernel<<<dim3(86, 64), 256, 0, stream>>>(Xsel, WgT, WuT, b_gate, b_up, act);
  gemm2_kernel<<<dim3(16, 64), 256, 0, stream>>>(act, WdT, b_down, selTok, selW, y);
}

// Round 3
// 1028.290 us; speedup vs baseline: 1.4956x; 1.1261x over previous
//
#include <hip/hip_runtime.h>
#include <cstdint>
#include <cstddef>

#define N_TOK  8192
#define HDIM   2048
#define NEXP   8
#define KCAP   1024
#define DFF    5461
#define DFF_PB 5504   // padded N for WgT/WuT (rows of transposed weights)
#define DFF_PA 5472   // padded K for act / gemm2 (multiple of 32)

typedef unsigned short u16;
typedef short bf16x8 __attribute__((ext_vector_type(8)));
typedef float f32x4  __attribute__((ext_vector_type(4)));

__device__ __forceinline__ u16 f2bf(float f) {
  uint32_t u = __float_as_uint(f);
  uint32_t r = (u + 0x7FFFu + ((u >> 16) & 1u)) >> 16;
  return (u16)r;
}

__device__ __forceinline__ uint32_t rotl32(uint32_t v, int d) {
  return (v << d) | (v >> (32 - d));
}

// JAX threefry2x32, key = (0, 42), partitionable scheme: counter=(0,i), bits = x0^x1.
__device__ uint32_t threefry_bits(uint32_t idx) {
  const uint32_t ks0 = 0u, ks1 = 42u, ks2 = 0u ^ 42u ^ 0x1BD11BDAu;
  uint32_t x0 = 0u + ks0;
  uint32_t x1 = idx + ks1;
#define TFR(d) { x0 += x1; x1 = rotl32(x1, d); x1 ^= x0; }
  TFR(13) TFR(15) TFR(26) TFR(6)
  x0 += ks1; x1 += ks2 + 1u;
  TFR(17) TFR(29) TFR(16) TFR(24)
  x0 += ks2; x1 += ks0 + 2u;
  TFR(13) TFR(15) TFR(26) TFR(6)
  x0 += ks0; x1 += ks1 + 3u;
  TFR(17) TFR(29) TFR(16) TFR(24)
  x0 += ks1; x1 += ks2 + 4u;
  TFR(13) TFR(15) TFR(26) TFR(6)
  x0 += ks2; x1 += ks0 + 5u;
#undef TFR
  return x0 ^ x1;
}

// ---------------- router: clean_h + gumbel -> softmax, stored transposed [E][n_tok]
__global__ __launch_bounds__(256) void router_kernel(const float* __restrict__ x,
    const float* __restrict__ rw, const float* __restrict__ rb,
    float* __restrict__ SmT)
{
  const int lane = threadIdx.x & 63;
  const int wid  = threadIdx.x >> 6;
  const int t = blockIdx.x * 4 + wid;     // one token per wave
  const float* xr = x + (size_t)t * HDIM;
  float acc[8] = {0.f,0.f,0.f,0.f,0.f,0.f,0.f,0.f};
#pragma unroll
  for (int it = 0; it < HDIM / 64; ++it) {
    int h = lane + it * 64;
    float xv = xr[h];
    const float4* wp = (const float4*)(rw + h * 8);
    float4 w0 = wp[0], w1 = wp[1];
    acc[0] = fmaf(xv, w0.x, acc[0]);
    acc[1] = fmaf(xv, w0.y, acc[1]);
    acc[2] = fmaf(xv, w0.z, acc[2]);
    acc[3] = fmaf(xv, w0.w, acc[3]);
    acc[4] = fmaf(xv, w1.x, acc[4]);
    acc[5] = fmaf(xv, w1.y, acc[5]);
    acc[6] = fmaf(xv, w1.z, acc[6]);
    acc[7] = fmaf(xv, w1.w, acc[7]);
  }
#pragma unroll
  for (int m = 32; m >= 1; m >>= 1) {
#pragma unroll
    for (int e = 0; e < 8; ++e) acc[e] += __shfl_xor(acc[e], m, 64);
  }
  if (lane == 0) {
    float h[8];
#pragma unroll
    for (int e = 0; e < 8; ++e) {
      uint32_t bits = threefry_bits((uint32_t)(t * 8 + e));
      float u = __uint_as_float((bits >> 9) | 0x3f800000u) - 1.0f;
      u = fmaxf(u, 0.0f);
      float g = -logf(-logf(u + 1e-10f) + 1e-10f);
      h[e] = acc[e] + rb[e] + g;
    }
    float mx = h[0];
#pragma unroll
    for (int e = 1; e < 8; ++e) mx = fmaxf(mx, h[e]);
    float ex[8]; float s = 0.f;
#pragma unroll
    for (int e = 0; e < 8; ++e) { ex[e] = expf(h[e] - mx); s += ex[e]; }
#pragma unroll
    for (int e = 0; e < 8; ++e) SmT[e * N_TOK + t] = ex[e] / s;
  }
}

// ---------------- exact top-1024-of-8192 per expert via 4-pass radix select
__global__ __launch_bounds__(1024) void select_topk(const float* __restrict__ SmT,
    uint32_t* __restrict__ selTok, float* __restrict__ selW)
{
  const int e = blockIdx.x;
  const int tid = threadIdx.x;
  const float* v = SmT + (size_t)e * N_TOK;
  __shared__ uint32_t hist[256];
  __shared__ uint32_t sh_byte, sh_kk, sh_cnt, sh_eqc;
  uint32_t bitsv[8];
#pragma unroll
  for (int i = 0; i < 8; ++i) bitsv[i] = __float_as_uint(v[tid + i * 1024]);
  uint32_t prefix = 0;
  uint32_t kk = KCAP;
  for (int s = 3; s >= 0; --s) {
    if (tid < 256) hist[tid] = 0;
    __syncthreads();
    uint32_t himask = (s == 3) ? 0u : (0xFFFFFFFFu << ((s + 1) * 8));
#pragma unroll
    for (int i = 0; i < 8; ++i) {
      uint32_t b = bitsv[i];
      if ((b & himask) == prefix) atomicAdd(&hist[(b >> (s * 8)) & 255u], 1u);
    }
    __syncthreads();
    if (tid == 0) {
      uint32_t cum = 0; uint32_t bsel = 0, kn = kk;
      for (int b = 255; b >= 0; --b) {
        uint32_t c = hist[b];
        if (cum + c >= kk) { bsel = (uint32_t)b; kn = kk - cum; break; }
        cum += c;
      }
      sh_byte = bsel; sh_kk = kn;
    }
    __syncthreads();
    prefix |= sh_byte << (s * 8);
    kk = sh_kk;
  }
  const uint32_t T = prefix;
  const uint32_t need = kk;
  if (tid == 0) { sh_cnt = 0; sh_eqc = 0; }
  __syncthreads();
#pragma unroll
  for (int i = 0; i < 8; ++i) {
    uint32_t b = bitsv[i];
    if (b > T) {
      uint32_t p = atomicAdd(&sh_cnt, 1u);
      selTok[e * KCAP + p] = (uint32_t)(tid + i * 1024);
      selW[e * KCAP + p] = __uint_as_float(b);
    } else if (b == T) {
      atomicAdd(&sh_eqc, 1u);
    }
  }
  __syncthreads();
  if (sh_eqc == need) {
#pragma unroll
    for (int i = 0; i < 8; ++i) {
      if (bitsv[i] == T) {
        uint32_t p = atomicAdd(&sh_cnt, 1u);
        selTok[e * KCAP + p] = (uint32_t)(tid + i * 1024);
        selW[e * KCAP + p] = __uint_as_float(T);
      }
    }
  } else if (tid == 0) {
    uint32_t p = sh_cnt, rem = need;
    for (int t = 0; t < N_TOK && rem > 0u; ++t) {
      if (__float_as_uint(v[t]) == T) {
        selTok[e * KCAP + p] = (uint32_t)t;
        selW[e * KCAP + p] = __uint_as_float(T);
        ++p; --rem;
      }
    }
  }
}

// ---------------- gather selected token rows, fp32 -> bf16
__global__ __launch_bounds__(256) void gather_kernel(const float* __restrict__ x,
    const uint32_t* __restrict__ selTok, u16* __restrict__ Xsel)
{
  const int slot = blockIdx.x;
  const int tid = threadIdx.x;
  const uint32_t tok = selTok[slot];
  const float4* src = (const float4*)(x + (size_t)tok * HDIM);
  float4 a = src[tid * 2], b = src[tid * 2 + 1];
  union { u16 h[8]; uint4 vv; } pk;
  pk.h[0] = f2bf(a.x); pk.h[1] = f2bf(a.y); pk.h[2] = f2bf(a.z); pk.h[3] = f2bf(a.w);
  pk.h[4] = f2bf(b.x); pk.h[5] = f2bf(b.y); pk.h[6] = f2bf(b.z); pk.h[7] = f2bf(b.w);
  ((uint4*)(Xsel + (size_t)slot * HDIM))[tid] = pk.vv;
}

// ---------------- zero the K-pad columns of act (cols DFF..DFF_PA)
__global__ __launch_bounds__(256) void pad_act_kernel(u16* __restrict__ act) {
  int idx = blockIdx.x * 256 + threadIdx.x;   // 8192*11 total
  int row = idx / 11, col = idx % 11;
  act[(size_t)row * DFF_PA + (DFF + col)] = 0;
}

// ---------------- transpose + fp32->bf16: out[j][i] = in[i][j], zero-padded
__global__ __launch_bounds__(256) void transpose_convert(const float* __restrict__ in,
    int rows_in, int cols_in, u16* __restrict__ out, int out_cols)
{
  __shared__ float tile[32][33];
  const int bi = blockIdx.y;
  const int bj = blockIdx.x;
  const int tx = threadIdx.x, ty = threadIdx.y;
#pragma unroll
  for (int t = 0; t < 4; ++t) {
    int r = bi * 32 + ty + t * 8, c = bj * 32 + tx;
    float vv = (r < rows_in && c < cols_in) ? in[(size_t)r * cols_in + c] : 0.0f;
    tile[ty + t * 8][tx] = vv;
  }
  __syncthreads();
#pragma unroll
  for (int t = 0; t < 4; ++t) {
    int oj = bj * 32 + ty + t * 8;
    int oi = bi * 32 + tx;
    out[(size_t)oj * out_cols + oi] = f2bf(tile[tx][ty + t * 8]);
  }
}

// ---------------- async global->LDS staging helper
#if defined(__has_builtin)
#  if __has_builtin(__builtin_amdgcn_global_load_lds)
#    define HAVE_GLD 1
#  endif
#endif
#ifdef HAVE_GLD
#define GLD16(gp, lp) __builtin_amdgcn_global_load_lds( \
    (const __attribute__((address_space(1))) void*)(gp), \
    (__attribute__((address_space(3))) void*)(lp), 16, 0, 0)
#endif

// ---------------- GEMM1: act = silu(Xsel*WgT + bg) .* (Xsel*WuT + bu), bf16 out
// Block tile 128(M) x 64(N). XOR-4 LDS swizzle (applied on the staging SOURCE
// index; GLD16 destinations stay wave-contiguous). Supertile dispatch: 8-bn
// supercolumns, bm-fast (512 blocks = one supercol co-resident; B group 4 MB).
__global__ __launch_bounds__(256, 2) void gemm1_kernel(
    const u16* __restrict__ Xsel,  // [8192][2048] bf16
    const u16* __restrict__ WgT,   // [5504][2048] bf16 (N-major, K-contig)
    const u16* __restrict__ WuT,   // [5504][2048]
    const float* __restrict__ bg, const float* __restrict__ bu,
    u16* __restrict__ act)         // [8192][5472] bf16
{
  const int id = blockIdx.x;
  const int sc = id >> 9;            // supercolumn (8 bn each)
  const int rem = id & 511;
  const int bm = rem & 63;
  const int bn = sc * 8 + (rem >> 6);
  if (bn >= 86) return;

  __shared__ u16 As [128 * 32];  // 8 KB
  __shared__ u16 Bgs[ 64 * 32];  // 4 KB
  __shared__ u16 Bus[ 64 * 32];  // 4 KB
  const int tid = threadIdx.x;
  const int lane = tid & 63, wid = tid >> 6;
  const int wr = wid >> 1, wc = wid & 1;
  // staging chunks (16B): A 512 -> 2/thread; Bg,Bu 256 each -> 1/thread each.
  // XOR swizzle: LDS chunk (row, p) holds global k-chunk (p ^ (row&3)).
  const int c0 = tid, c1 = tid + 256;
  const int r0 = c0 >> 2, ko0 = ((c0 & 3) ^ (r0 & 3)) * 8;
  const int r1 = c1 >> 2, ko1 = ((c1 & 3) ^ (r1 & 3)) * 8;
  const int rbq = tid >> 2, kob = ((tid & 3) ^ (rbq & 3)) * 8;

  const u16* a_g0  = Xsel + (size_t)(bm * 128 + r0) * HDIM + ko0;
  const u16* a_g1  = Xsel + (size_t)(bm * 128 + r1) * HDIM + ko1;
  const u16* bg_g  = WgT  + (size_t)(bn * 64 + rbq) * HDIM + kob;
  const u16* bu_g  = WuT  + (size_t)(bn * 64 + rbq) * HDIM + kob;
  u16* a_l0 = As  + c0 * 8; u16* a_l1 = As + c1 * 8;
  u16* g_l  = Bgs + tid * 8;
  u16* u_l  = Bus + tid * 8;

  f32x4 accg[4][2], accu[4][2];
  const f32x4 z4 = {0.f, 0.f, 0.f, 0.f};
#pragma unroll
  for (int i = 0; i < 4; ++i)
#pragma unroll
    for (int j = 0; j < 2; ++j) { accg[i][j] = z4; accu[i][j] = z4; }

  const int fr = lane & 15;
  const int ck = lane >> 4;                 // k-chunk 0..3 (fk = ck*8)
  const int sw = ck ^ (fr & 3);             // swizzled chunk (rows +16 keep fr&3)
  const int aoff = (wr * 64 + fr) * 32 + sw * 8;
  const int boff = (wc * 32 + fr) * 32 + sw * 8;

  for (int k0 = 0; k0 < HDIM; k0 += 32) {
#ifdef HAVE_GLD
    GLD16(a_g0 + k0, a_l0); GLD16(a_g1 + k0, a_l1);
    GLD16(bg_g + k0, g_l);  GLD16(bu_g + k0, u_l);
#else
    *(bf16x8*)a_l0 = *(const bf16x8*)(a_g0 + k0);
    *(bf16x8*)a_l1 = *(const bf16x8*)(a_g1 + k0);
    *(bf16x8*)g_l  = *(const bf16x8*)(bg_g + k0);
    *(bf16x8*)u_l  = *(const bf16x8*)(bu_g + k0);
#endif
    __syncthreads();
    bf16x8 af[4], bgf[2], buf2[2];
#pragma unroll
    for (int i = 0; i < 4; ++i) af[i] = *(const bf16x8*)&As[aoff + i * 16 * 32];
#pragma unroll
    for (int j = 0; j < 2; ++j) {
      bgf[j]  = *(const bf16x8*)&Bgs[boff + j * 16 * 32];
      buf2[j] = *(const bf16x8*)&Bus[boff + j * 16 * 32];
    }
#pragma unroll
    for (int i = 0; i < 4; ++i)
#pragma unroll
      for (int j = 0; j < 2; ++j) {
        accg[i][j] = __builtin_amdgcn_mfma_f32_16x16x32_bf16(af[i], bgf[j],  accg[i][j], 0, 0, 0);
        accu[i][j] = __builtin_amdgcn_mfma_f32_16x16x32_bf16(af[i], buf2[j], accu[i][j], 0, 0, 0);
      }
    __syncthreads();
  }
  const int rv = (lane >> 4) * 4;
#pragma unroll
  for (int i = 0; i < 4; ++i) {
#pragma unroll
    for (int v = 0; v < 4; ++v) {
      const int row = bm * 128 + wr * 64 + i * 16 + rv + v;
      u16* arow = act + (size_t)row * DFF_PA;
#pragma unroll
      for (int j = 0; j < 2; ++j) {
        const int col = bn * 64 + wc * 32 + j * 16 + fr;
        if (col < DFF) {
          float gv = accg[i][j][v] + bg[col];
          float uv = accu[i][j][v] + bu[col];
          float sv = gv / (1.0f + expf(-gv));   // silu
          arow[col] = f2bf(sv * uv);
        }
      }
    }
  }
}

// ---------------- GEMM2: y[tok] += G * (act*WdT + bd)  (fp32 atomics)
// 128x128 tile; same XOR swizzle + 8-bn supercolumn dispatch (2 supercols).
__global__ __launch_bounds__(256, 2) void gemm2_kernel(
    const u16* __restrict__ act,   // [8192][5472] bf16
    const u16* __restrict__ WdT,   // [2048][5472] bf16
    const float* __restrict__ bd,  // [2048]
    const uint32_t* __restrict__ selTok,
    const float* __restrict__ selW,
    float* __restrict__ y)         // [8192][2048] fp32
{
  const int id = blockIdx.x;
  const int sc = id >> 9;
  const int rem = id & 511;
  const int bm = rem & 63;
  const int bn = sc * 8 + (rem >> 6);

  __shared__ u16 As[128 * 32];
  __shared__ u16 Bs[128 * 32];
  const int tid = threadIdx.x;
  const int lane = tid & 63, wid = tid >> 6;
  const int wr = wid >> 1, wc = wid & 1;
  const int c0 = tid, c1 = tid + 256;
  const int r0 = c0 >> 2, ko0 = ((c0 & 3) ^ (r0 & 3)) * 8;
  const int r1 = c1 >> 2, ko1 = ((c1 & 3) ^ (r1 & 3)) * 8;

  const u16* a_g0 = act + (size_t)(bm * 128 + r0) * DFF_PA + ko0;
  const u16* a_g1 = act + (size_t)(bm * 128 + r1) * DFF_PA + ko1;
  const u16* b_g0 = WdT + (size_t)(bn * 128 + r0) * DFF_PA + ko0;
  const u16* b_g1 = WdT + (size_t)(bn * 128 + r1) * DFF_PA + ko1;
  u16* a_l0 = As + c0 * 8; u16* a_l1 = As + c1 * 8;
  u16* b_l0 = Bs + c0 * 8; u16* b_l1 = Bs + c1 * 8;

  f32x4 acc[4][4];
  const f32x4 z4 = {0.f, 0.f, 0.f, 0.f};
#pragma unroll
  for (int i = 0; i < 4; ++i)
#pragma unroll
    for (int j = 0; j < 4; ++j) acc[i][j] = z4;

  const int fr = lane & 15;
  const int ck = lane >> 4;
  const int sw = ck ^ (fr & 3);
  const int aoff = (wr * 64 + fr) * 32 + sw * 8;
  const int boff = (wc * 64 + fr) * 32 + sw * 8;

  for (int k0 = 0; k0 < DFF_PA; k0 += 32) {
#ifdef HAVE_GLD
    GLD16(a_g0 + k0, a_l0); GLD16(a_g1 + k0, a_l1);
    GLD16(b_g0 + k0, b_l0); GLD16(b_g1 + k0, b_l1);
#else
    *(bf16x8*)a_l0 = *(const bf16x8*)(a_g0 + k0);
    *(bf16x8*)a_l1 = *(const bf16x8*)(a_g1 + k0);
    *(bf16x8*)b_l0 = *(const bf16x8*)(b_g0 + k0);
    *(bf16x8*)b_l1 = *(const bf16x8*)(b_g1 + k0);
#endif
    __syncthreads();
    bf16x8 af[4], bf[4];
#pragma unroll
    for (int i = 0; i < 4; ++i) af[i] = *(const bf16x8*)&As[aoff + i * 16 * 32];
#pragma unroll
    for (int j = 0; j < 4; ++j) bf[j] = *(const bf16x8*)&Bs[boff + j * 16 * 32];
#pragma unroll
    for (int i = 0; i < 4; ++i)
#pragma unroll
      for (int j = 0; j < 4; ++j)
        acc[i][j] = __builtin_amdgcn_mfma_f32_16x16x32_bf16(af[i], bf[j], acc[i][j], 0, 0, 0);
    __syncthreads();
  }
  const int rv = (lane >> 4) * 4;
#pragma unroll
  for (int i = 0; i < 4; ++i) {
#pragma unroll
    for (int v = 0; v < 4; ++v) {
      const int row = bm * 128 + wr * 64 + i * 16 + rv + v;   // slot
      const uint32_t tok = selTok[row];
      const float w = selW[row];
      float* yrow = y + (size_t)tok * HDIM;
#pragma unroll
      for (int j = 0; j < 4; ++j) {
        const int col = bn * 128 + wc * 64 + j * 16 + fr;
        atomicAdd(&yrow[col], w * (acc[i][j][v] + bd[col]));
      }
    }
  }
}

extern "C" void kernel_launch(void* const* d_in, const int* in_sizes, int n_in,
                              void* d_out, int out_size, void* d_ws, size_t ws_size,
                              hipStream_t stream) {
  const float* x      = (const float*)d_in[0];
  const float* rw     = (const float*)d_in[1];
  const float* rb     = (const float*)d_in[2];
  const float* w_gate = (const float*)d_in[3];
  const float* b_gate = (const float*)d_in[4];
  const float* w_up   = (const float*)d_in[5];
  const float* b_up   = (const float*)d_in[6];
  const float* w_down = (const float*)d_in[7];
  const float* b_down = (const float*)d_in[8];
  float* y = (float*)d_out;

  uint8_t* ws = (uint8_t*)d_ws;
  float*    SmT    = (float*)(ws + 0);              //   262144 B
  uint32_t* selTok = (uint32_t*)(ws + 262144);      //    32768 B
  float*    selW   = (float*)(ws + 294912);         //    32768 B
  u16*      Xsel   = (u16*)(ws + 327680);           // 33554432 B
  u16*      WgT    = (u16*)(ws + 33882112ull);      // 22544384 B
  u16*      WuT    = (u16*)(ws + 56426496ull);      // 22544384 B
  u16*      WdT    = (u16*)(ws + 78970880ull);      // 22413312 B
  u16*      act    = (u16*)(ws + 101384192ull);     // 89653248 B

  hipMemsetAsync(d_out, 0, (size_t)N_TOK * HDIM * sizeof(float), stream);
  transpose_convert<<<dim3(172, 64), dim3(32, 8), 0, stream>>>(w_gate, 2048, DFF, WgT, 2048);
  transpose_convert<<<dim3(172, 64), dim3(32, 8), 0, stream>>>(w_up,   2048, DFF, WuT, 2048);
  transpose_convert<<<dim3(64, 171), dim3(32, 8), 0, stream>>>(w_down, DFF, 2048, WdT, DFF_PA);
  router_kernel<<<N_TOK / 4, 256, 0, stream>>>(x, rw, rb, SmT);
  select_topk<<<NEXP, 1024, 0, stream>>>(SmT, selTok, selW);
  gather_kernel<<<N_TOK, 256, 0, stream>>>(x, selTok, Xsel);
  pad_act_kernel<<<(N_TOK * 11) / 256, 256, 0, stream>>>(act);
  gemm1_kernel<<<11 * 512, 256, 0, stream>>>(Xsel, WgT, WuT, b_gate, b_up, act);
  gemm2_kernel<<<2 * 512, 256, 0, stream>>>(act, WdT, b_down, selTok, selW, y);
}